// Round 5
// baseline (456.311 us; speedup 1.0000x reference)
//
#include <hip/hip_runtime.h>
#include <hip/hip_bf16.h>

typedef __bf16 bf16_t;
typedef __bf16 bf16x8 __attribute__((ext_vector_type(8)));
typedef float  f32x4  __attribute__((ext_vector_type(4)));

#define BS 512
#define LH 100
#define NC 64
#define DD 256
#define IC 256
#define KK 32

// ---------------------------------------------------------------------------
// workspace layout (bytes), peak 23,330,816 (proven-safe extent from R4):
//  [0, 6,553,600)        S fp32 [51200][32] -> attn fp32 [512][32][100] in-place
//                        -> wm fp32 [512][64][32] (4.19MB) after k4
//  [6,553,600, +393,216) W bf16 planes Wh/Wl/Wl2 (3 x 131,072)   [dead after k12]
//  [6,946,816, +49,152)  C bf16 planes Ch/Cl/Cl2 (3 x 16,384)    [dead after k12]
//  [6,553,600, 23,330,816) I fp32 [512][32][256] (k4 writes; overlaps dead planes)
// ---------------------------------------------------------------------------
#define OFF_WPL 6553600
#define OFF_CPL (6553600 + 3 * 131072)
#define OFF_I   6553600

// split fp32 into 3 bf16 terms: v == h + l + l2 exactly (24-bit mantissa coverage)
__device__ __forceinline__ void split3(float v, bf16_t& h, bf16_t& l, bf16_t& l2) {
    h = (bf16_t)v;  float r1 = v - (float)h;
    l = (bf16_t)r1; float r2 = r1 - (float)l;
    l2 = (bf16_t)r2;
}

__device__ __forceinline__ void split3x8(const float* v, bf16x8& h, bf16x8& l, bf16x8& l2) {
#pragma unroll
    for (int j = 0; j < 8; j++) {
        bf16_t a, b, c;
        split3(v[j], a, b, c);
        h[j] = a; l[j] = b; l2[j] = c;
    }
}

// fp32-faithful 16x16x32 MFMA: (ah+al+al2)*(bh+bl+bl2), 6 kept terms,
// main term in accM, corrections in accC (|corr| ~ 2^-9 of main).
__device__ __forceinline__ void mfma6(const bf16x8& ah, const bf16x8& al, const bf16x8& al2,
                                      const bf16x8& bh, const bf16x8& bl, const bf16x8& bl2,
                                      f32x4& accM, f32x4& accC) {
    accM = __builtin_amdgcn_mfma_f32_16x16x32_bf16(ah,  bh,  accM, 0, 0, 0);
    accC = __builtin_amdgcn_mfma_f32_16x16x32_bf16(ah,  bl,  accC, 0, 0, 0);
    accC = __builtin_amdgcn_mfma_f32_16x16x32_bf16(al,  bh,  accC, 0, 0, 0);
    accC = __builtin_amdgcn_mfma_f32_16x16x32_bf16(ah,  bl2, accC, 0, 0, 0);
    accC = __builtin_amdgcn_mfma_f32_16x16x32_bf16(al,  bl,  accC, 0, 0, 0);
    accC = __builtin_amdgcn_mfma_f32_16x16x32_bf16(al2, bh,  accC, 0, 0, 0);
}

// ---------------------------------------------------------------------------
// KP: pre-split W (65536) and C (8192) fp32 -> 3 bf16 planes each
// ---------------------------------------------------------------------------
__global__ __launch_bounds__(256) void kp_split(const float* __restrict__ W,
                                                const float* __restrict__ C,
                                                bf16_t* __restrict__ Wh, bf16_t* __restrict__ Wl,
                                                bf16_t* __restrict__ Wl2,
                                                bf16_t* __restrict__ Ch, bf16_t* __restrict__ Cl,
                                                bf16_t* __restrict__ Cl2) {
    int idx = blockIdx.x * 256 + threadIdx.x;
    if (idx < 65536) {
        bf16_t h, l, l2;
        split3(W[idx], h, l, l2);
        Wh[idx] = h; Wl[idx] = l; Wl2[idx] = l2;
    } else {
        int i = idx - 65536;
        if (i < 8192) {
            bf16_t h, l, l2;
            split3(C[i], h, l, l2);
            Ch[i] = h; Cl[i] = l; Cl2[i] = l2;
        }
    }
}

// ---------------------------------------------------------------------------
// K12: P = tanh(H W^T) (fp32-faithful, fp64 tanh, regs->LDS);
//      S = P C^T (fp32-faithful). One wave per 16-row m-tile.
// ---------------------------------------------------------------------------
__global__ __launch_bounds__(256) void k12_proj_scores(const float* __restrict__ H,
                                                       const bf16_t* __restrict__ Wh,
                                                       const bf16_t* __restrict__ Wl,
                                                       const bf16_t* __restrict__ Wl2,
                                                       const bf16_t* __restrict__ Ch,
                                                       const bf16_t* __restrict__ Cl,
                                                       const bf16_t* __restrict__ Cl2,
                                                       float* __restrict__ S) {
    const int wave = threadIdx.x >> 6;
    const int lane = threadIdx.x & 63;
    const int r = lane & 15, q = lane >> 4;
    const int mt = blockIdx.x * 4 + wave;
    const int m0 = mt * 16;

    __shared__ float pl[4][16 * 66];
    float* myp = pl[wave];

    const float* arow = H + (size_t)(m0 + r) * DD + q * 8;

    const f32x4 zero = {0.f, 0.f, 0.f, 0.f};
    f32x4 saccM[2], saccC[2];
    saccM[0] = zero; saccM[1] = zero; saccC[0] = zero; saccC[1] = zero;

    for (int c4 = 0; c4 < 4; c4++) {
        // ---- stage 1: P-tile chunk (cols c4*64 .. +64) ----
        f32x4 aM[4], aC[4];
#pragma unroll
        for (int t = 0; t < 4; t++) { aM[t] = zero; aC[t] = zero; }

        for (int ks = 0; ks < 8; ks++) {
            float av[8];
            const float* ap = arow + ks * 32;
            float4 u = *(const float4*)ap;
            float4 v = *(const float4*)(ap + 4);
            av[0]=u.x; av[1]=u.y; av[2]=u.z; av[3]=u.w;
            av[4]=v.x; av[5]=v.y; av[6]=v.z; av[7]=v.w;
            bf16x8 ah, al, al2;
            split3x8(av, ah, al, al2);
#pragma unroll
            for (int t = 0; t < 4; t++) {
                const size_t base = (size_t)((c4 * 4 + t) * 16 + r) * DD + ks * 32 + q * 8;
                bf16x8 bh  = *(const bf16x8*)(Wh  + base);
                bf16x8 bl  = *(const bf16x8*)(Wl  + base);
                bf16x8 bl2 = *(const bf16x8*)(Wl2 + base);
                mfma6(ah, al, al2, bh, bl, bl2, aM[t], aC[t]);
            }
        }
#pragma unroll
        for (int t = 0; t < 4; t++)
#pragma unroll
            for (int i = 0; i < 4; i++) {
                float s1 = aM[t][i] + aC[t][i];
                myp[(q * 4 + i) * 66 + t * 16 + r] = (float)tanh((double)s1);
            }
        __syncthreads();

        // ---- stage 2: S += P_chunk @ C_chunk^T ----
#pragma unroll
        for (int ks2 = 0; ks2 < 2; ks2++) {
            const float* src = myp + r * 66 + ks2 * 32 + q * 8;
            float pv[8];
#pragma unroll
            for (int j = 0; j < 8; j++) pv[j] = src[j];
            bf16x8 ph, plo, pl2;
            split3x8(pv, ph, plo, pl2);
            const int cbase = c4 * 64 + ks2 * 32 + q * 8;
#pragma unroll
            for (int ntS = 0; ntS < 2; ntS++) {
                const size_t base = (size_t)(ntS * 16 + r) * IC + cbase;
                bf16x8 ch  = *(const bf16x8*)(Ch  + base);
                bf16x8 cl  = *(const bf16x8*)(Cl  + base);
                bf16x8 cl2 = *(const bf16x8*)(Cl2 + base);
                mfma6(ph, plo, pl2, ch, cl, cl2, saccM[ntS], saccC[ntS]);
            }
        }
        __syncthreads();
    }

#pragma unroll
    for (int ntS = 0; ntS < 2; ntS++)
#pragma unroll
        for (int i = 0; i < 4; i++)
            S[(size_t)(m0 + q * 4 + i) * KK + ntS * 16 + r] = saccM[ntS][i] + saccC[ntS][i];
}

// ---------------------------------------------------------------------------
// K3: softmax over l per (b,k), fp64 math; masked rows (k >= ni[b]) -> 1/100.
// In-place: attn fp32 [b][32][100] over the S_b region.
// ---------------------------------------------------------------------------
__global__ __launch_bounds__(256) void k3_softmax(float* __restrict__ Sa,
                                                  const int* __restrict__ ni) {
    const int b = blockIdx.x;
    float* Sb = Sa + (size_t)b * LH * KK;
    __shared__ float ls[LH * KK];
    __shared__ double red[8][KK + 1];

    for (int i = threadIdx.x; i < LH * KK; i += 256) ls[i] = Sb[i];
    __syncthreads();

    const int k = threadIdx.x & 31;
    const int grp = threadIdx.x >> 5;
    const int nib = ni[b];

    double vals[13];
    int cnt = 0;
    double vmax = -1e300;
    for (int l = grp; l < LH; l += 8) {
        double v = (double)ls[l * KK + k];
        vals[cnt++] = v;
        vmax = fmax(vmax, v);
    }
    red[grp][k] = vmax;
    __syncthreads();
    if (grp == 0) {
        double m = red[0][k];
        for (int j = 1; j < 8; j++) m = fmax(m, red[j][k]);
        red[0][k] = m;
    }
    __syncthreads();
    const double mx = red[0][k];
    __syncthreads();

    double s = 0.0;
    for (int i = 0; i < cnt; i++) {
        double e = exp(vals[i] - mx);
        vals[i] = e;
        s += e;
    }
    red[grp][k] = s;
    __syncthreads();
    if (grp == 0) {
        double t = 0.0;
        for (int j = 0; j < 8; j++) t += red[j][k];
        red[0][k] = t;
    }
    __syncthreads();
    const double inv = 1.0 / red[0][k];

    float* ab = Sb + k * LH;
    const bool masked = (k >= nib);
    cnt = 0;
    for (int l = grp; l < LH; l += 8) {
        ab[l] = masked ? 0.01f : (float)(vals[cnt] * inv);
        cnt++;
    }
}

// ---------------------------------------------------------------------------
// K4: I[k][d] = sum_l attn[k][l] * H[l][d] (per b), fp32-faithful, fp32 out.
// ---------------------------------------------------------------------------
__global__ __launch_bounds__(256) void k4_interests(const float* __restrict__ attn,
                                                    const float* __restrict__ H,
                                                    float* __restrict__ I) {
    const int b = blockIdx.x;
    const int wave = threadIdx.x >> 6;
    const int lane = threadIdx.x & 63;
    const int r = lane & 15, q = lane >> 4;

    const float* Ab = attn + (size_t)b * KK * LH;
    const float* Hb = H + (size_t)b * LH * DD;

    for (int job = wave; job < 32; job += 4) {
        const int mt = job & 1, nt = job >> 1;
        const int m0 = mt * 16, n0 = nt * 16;
        const f32x4 zero = {0.f, 0.f, 0.f, 0.f};
        f32x4 accM = zero, accC = zero;
#pragma unroll
        for (int ks = 0; ks < 4; ks++) {
            const int l0 = ks * 32 + q * 8;
            float av[8], bv[8];
#pragma unroll
            for (int j = 0; j < 8; j++) {
                int l = l0 + j;
                av[j] = (l < LH) ? Ab[(size_t)(m0 + r) * LH + l] : 0.f;
                bv[j] = (l < LH) ? Hb[(size_t)l * DD + n0 + r] : 0.f;
            }
            bf16x8 ah, al, al2, bh, bl, bl2;
            split3x8(av, ah, al, al2);
            split3x8(bv, bh, bl, bl2);
            mfma6(ah, al, al2, bh, bl, bl2, accM, accC);
        }
#pragma unroll
        for (int i = 0; i < 4; i++)
            I[((size_t)b * KK + m0 + q * 4 + i) * DD + n0 + r] = accM[i] + accC[i];
    }
}

// ---------------------------------------------------------------------------
// K5: w[n][k] = sum_d cand[n][d]*I[k][d] (fp32-faithful) + variable top-k mask.
// ---------------------------------------------------------------------------
__global__ __launch_bounds__(256) void k5_w_topk(const float* __restrict__ cand,
                                                 const float* __restrict__ I,
                                                 const int* __restrict__ cc,
                                                 float* __restrict__ wm) {
    const int b = blockIdx.x;
    const int wave = threadIdx.x >> 6;
    const int lane = threadIdx.x & 63;
    const int r = lane & 15, q = lane >> 4;

    __shared__ float shw[NC][KK + 1];

    const float* Cb = cand + (size_t)b * NC * DD;
    const float* Ib = I + (size_t)b * KK * DD;

    for (int job = wave; job < 8; job += 4) {
        const int mt = job >> 1, nt = job & 1;
        const int m0 = mt * 16, n0 = nt * 16;
        const f32x4 zero = {0.f, 0.f, 0.f, 0.f};
        f32x4 accM = zero, accC = zero;
#pragma unroll
        for (int ks = 0; ks < 8; ks++) {
            const float* ap = Cb + (size_t)(m0 + r) * DD + ks * 32 + q * 8;
            const float* bp = Ib + (size_t)(n0 + r) * DD + ks * 32 + q * 8;
            float av[8], bv[8];
            float4 u1 = *(const float4*)ap;      float4 u2 = *(const float4*)(ap + 4);
            float4 v1 = *(const float4*)bp;      float4 v2 = *(const float4*)(bp + 4);
            av[0]=u1.x; av[1]=u1.y; av[2]=u1.z; av[3]=u1.w;
            av[4]=u2.x; av[5]=u2.y; av[6]=u2.z; av[7]=u2.w;
            bv[0]=v1.x; bv[1]=v1.y; bv[2]=v1.z; bv[3]=v1.w;
            bv[4]=v2.x; bv[5]=v2.y; bv[6]=v2.z; bv[7]=v2.w;
            bf16x8 ah, al, al2, bh, bl, bl2;
            split3x8(av, ah, al, al2);
            split3x8(bv, bh, bl, bl2);
            mfma6(ah, al, al2, bh, bl, bl2, accM, accC);
        }
#pragma unroll
        for (int i = 0; i < 4; i++) shw[m0 + q * 4 + i][n0 + r] = accM[i] + accC[i];
    }
    __syncthreads();

    if (threadIdx.x < NC) {
        const int n = threadIdx.x;
        int c8 = 8 * cc[b];
        int dynK = 32 - __clz(c8 - 1);      // ceil(log2(8c)), exact for c in [1,18]
        dynK = min(max(dynK, 1), KK);
        float v[KK];
        for (int k = 0; k < KK; k++) v[k] = shw[n][k];
        float* dst = wm + ((size_t)b * NC + n) * KK;
        for (int k = 0; k < KK; k++) {
            int rank = 0;
            for (int j = 0; j < KK; j++)
                rank += (v[j] > v[k]) || (v[j] == v[k] && j < k);
            dst[k] = (rank < dynK) ? v[k] : 0.f;
        }
    }
}

// ---------------------------------------------------------------------------
// K6: user[n][d] = sum_k wm[n][k] * I[k][d]  (fp32 out)
// ---------------------------------------------------------------------------
__global__ __launch_bounds__(256) void k6_user(const float* __restrict__ I,
                                               const float* __restrict__ wm,
                                               float* __restrict__ out) {
    const int b = blockIdx.x;
    const int d = threadIdx.x;

    float icol[KK];
    const float* src = I + (size_t)b * KK * DD + d;
#pragma unroll
    for (int k = 0; k < KK; k++) icol[k] = src[(size_t)k * DD];

    const float* wb = wm + (size_t)b * NC * KK;
    for (int n = 0; n < NC; n++) {
        const float* wr = wb + n * KK;
        float acc = 0.f;
#pragma unroll
        for (int k = 0; k < KK; k++) acc += wr[k] * icol[k];
        out[((size_t)b * NC + n) * DD + d] = acc;
    }
}

// ---------------------------------------------------------------------------
extern "C" void kernel_launch(void* const* d_in, const int* in_sizes, int n_in,
                              void* d_out, int out_size, void* d_ws, size_t ws_size,
                              hipStream_t stream) {
    const float* hist = (const float*)d_in[0];
    // d_in[1] = history_mask (unused)
    const float* cand = (const float*)d_in[2];
    const int* ni = (const int*)d_in[3];
    const int* cc = (const int*)d_in[4];
    const float* W = (const float*)d_in[5];
    const float* C = (const float*)d_in[6];
    float* out = (float*)d_out;

    char* w8 = (char*)d_ws;
    float*  S   = (float*)(w8 + 0);                  // -> attn in-place -> wm
    float*  wm  = (float*)(w8 + 0);
    bf16_t* Wh  = (bf16_t*)(w8 + OFF_WPL);
    bf16_t* Wl  = (bf16_t*)(w8 + OFF_WPL + 131072);
    bf16_t* Wl2 = (bf16_t*)(w8 + OFF_WPL + 262144);
    bf16_t* Ch  = (bf16_t*)(w8 + OFF_CPL);
    bf16_t* Cl  = (bf16_t*)(w8 + OFF_CPL + 16384);
    bf16_t* Cl2 = (bf16_t*)(w8 + OFF_CPL + 32768);
    float*  I   = (float*)(w8 + OFF_I);              // overwrites dead planes

    kp_split<<<288, 256, 0, stream>>>(W, C, Wh, Wl, Wl2, Ch, Cl, Cl2);
    k12_proj_scores<<<800, 256, 0, stream>>>(hist, Wh, Wl, Wl2, Ch, Cl, Cl2, S);
    k3_softmax<<<BS, 256, 0, stream>>>(S, ni);
    k4_interests<<<BS, 256, 0, stream>>>(S, hist, I);
    k5_w_topk<<<BS, 256, 0, stream>>>(cand, I, cc, wm);
    k6_user<<<BS, 256, 0, stream>>>(I, wm, out);
}

// Round 6
// 376.622 us; speedup vs baseline: 1.2116x; 1.2116x over previous
//
#include <hip/hip_runtime.h>
#include <hip/hip_bf16.h>

typedef __bf16 bf16_t;
typedef __bf16 bf16x8 __attribute__((ext_vector_type(8)));
typedef float  f32x4  __attribute__((ext_vector_type(4)));

#define BS 512
#define LH 100
#define NC 64
#define DD 256
#define IC 256
#define KK 32

// workspace layout (bytes), peak 23,330,816 (proven-safe):
//  [0, 6,553,600)          S fp32 -> attn fp32 in-place -> wm fp32
//  [6,553,600, +393,216)   W bf16 planes (dead after k12)
//  [6,946,816, +49,152)    C bf16 planes (dead after k12)
//  [6,553,600, 23,330,816) I fp32 (k4 writes; overlaps dead planes)
#define OFF_WPL 6553600
#define OFF_CPL (6553600 + 3 * 131072)
#define OFF_I   6553600

// split fp32 into 3 bf16 terms: v == h + l + l2 exactly
__device__ __forceinline__ void split3(float v, bf16_t& h, bf16_t& l, bf16_t& l2) {
    h = (bf16_t)v;  float r1 = v - (float)h;
    l = (bf16_t)r1; float r2 = r1 - (float)l;
    l2 = (bf16_t)r2;
}

__device__ __forceinline__ void split3x8(const float* v, bf16x8& h, bf16x8& l, bf16x8& l2) {
#pragma unroll
    for (int j = 0; j < 8; j++) {
        bf16_t a, b, c;
        split3(v[j], a, b, c);
        h[j] = a; l[j] = b; l2[j] = c;
    }
}

// fp32-faithful 16x16x32 MFMA: 6 kept terms, main in accM, corrections in accC
__device__ __forceinline__ void mfma6(const bf16x8& ah, const bf16x8& al, const bf16x8& al2,
                                      const bf16x8& bh, const bf16x8& bl, const bf16x8& bl2,
                                      f32x4& accM, f32x4& accC) {
    accM = __builtin_amdgcn_mfma_f32_16x16x32_bf16(ah,  bh,  accM, 0, 0, 0);
    accC = __builtin_amdgcn_mfma_f32_16x16x32_bf16(ah,  bl,  accC, 0, 0, 0);
    accC = __builtin_amdgcn_mfma_f32_16x16x32_bf16(al,  bh,  accC, 0, 0, 0);
    accC = __builtin_amdgcn_mfma_f32_16x16x32_bf16(ah,  bl2, accC, 0, 0, 0);
    accC = __builtin_amdgcn_mfma_f32_16x16x32_bf16(al,  bl,  accC, 0, 0, 0);
    accC = __builtin_amdgcn_mfma_f32_16x16x32_bf16(al2, bh,  accC, 0, 0, 0);
}

// ---------------------------------------------------------------------------
// KP: pre-split W (65536) and C (8192) fp32 -> 3 bf16 planes each
// ---------------------------------------------------------------------------
__global__ __launch_bounds__(256) void kp_split(const float* __restrict__ W,
                                                const float* __restrict__ C,
                                                bf16_t* __restrict__ Wh, bf16_t* __restrict__ Wl,
                                                bf16_t* __restrict__ Wl2,
                                                bf16_t* __restrict__ Ch, bf16_t* __restrict__ Cl,
                                                bf16_t* __restrict__ Cl2) {
    int idx = blockIdx.x * 256 + threadIdx.x;
    if (idx < 65536) {
        bf16_t h, l, l2;
        split3(W[idx], h, l, l2);
        Wh[idx] = h; Wl[idx] = l; Wl2[idx] = l2;
    } else {
        int i = idx - 65536;
        if (i < 8192) {
            bf16_t h, l, l2;
            split3(C[i], h, l, l2);
            Ch[i] = h; Cl[i] = l; Cl2[i] = l2;
        }
    }
}

// ---------------------------------------------------------------------------
// K12: P = tanh(H W^T) (fp32-faithful, fp64 tanh), S = P C^T (fp32-faithful).
// Restructured: A split once into VGPRs; W planes staged per-32-row-chunk
// into LDS (padded stride, coalesced); values & accumulation order identical
// to the R5 passing kernel (bit-identical output).
// ---------------------------------------------------------------------------
#define WROW 280   // padded LDS row stride in bf16 (560B: 16B-aligned, 2-way banks)
__global__ __launch_bounds__(256) void k12_proj_scores(const float* __restrict__ H,
                                                       const bf16_t* __restrict__ Wh,
                                                       const bf16_t* __restrict__ Wl,
                                                       const bf16_t* __restrict__ Wl2,
                                                       const bf16_t* __restrict__ Ch,
                                                       const bf16_t* __restrict__ Cl,
                                                       const bf16_t* __restrict__ Cl2,
                                                       float* __restrict__ S) {
    __shared__ bf16_t wlds[3 * 32 * WROW];   // 53,760 B
    __shared__ float  pl[4][16 * 34];        //  8,704 B  (per-wave P chunk)

    const int tid = threadIdx.x;
    const int wave = tid >> 6;
    const int lane = tid & 63;
    const int r = lane & 15, q = lane >> 4;
    const int mt = blockIdx.x * 4 + wave;
    const int m0 = mt * 16;

    // ---- load + split A (H rows) once ----
    bf16x8 Ah[8], Al[8], Al2[8];
    {
        const float* arow = H + (size_t)(m0 + r) * DD + q * 8;
#pragma unroll
        for (int ks = 0; ks < 8; ks++) {
            const float* ap = arow + ks * 32;
            float4 u = *(const float4*)ap;
            float4 v = *(const float4*)(ap + 4);
            float av[8] = {u.x, u.y, u.z, u.w, v.x, v.y, v.z, v.w};
            split3x8(av, Ah[ks], Al[ks], Al2[ks]);
        }
    }

    const f32x4 zero = {0.f, 0.f, 0.f, 0.f};
    f32x4 saccM[2], saccC[2];
    saccM[0] = zero; saccM[1] = zero; saccC[0] = zero; saccC[1] = zero;

    float* myp = pl[wave];

    for (int c8 = 0; c8 < 8; c8++) {
        const int c0 = c8 * 32;
        __syncthreads();   // protect wlds of previous chunk
        // ---- cooperative stage of W-plane chunk rows [c0, c0+32) ----
        for (int g = tid; g < 3072; g += 256) {
            const int p = g >> 10, rem = g & 1023, row = rem >> 5, grp = rem & 31;
            const bf16_t* src = (p == 0) ? Wh : (p == 1) ? Wl : Wl2;
            bf16x8 v = *(const bf16x8*)(src + (size_t)(c0 + row) * DD + grp * 8);
            *(bf16x8*)(wlds + (p * 32 + row) * WROW + grp * 8) = v;
        }
        __syncthreads();

        // ---- stage 1: P-tile chunk (2 c-tiles of 16) ----
        f32x4 aM[2], aC[2];
        aM[0] = zero; aM[1] = zero; aC[0] = zero; aC[1] = zero;
#pragma unroll
        for (int ks = 0; ks < 8; ks++) {
#pragma unroll
            for (int ct = 0; ct < 2; ct++) {
                const int rowb = (ct * 16 + r) * WROW + ks * 32 + q * 8;
                bf16x8 bh  = *(const bf16x8*)(wlds + 0 * 32 * WROW + rowb);
                bf16x8 bl  = *(const bf16x8*)(wlds + 1 * 32 * WROW + rowb);
                bf16x8 bl2 = *(const bf16x8*)(wlds + 2 * 32 * WROW + rowb);
                mfma6(Ah[ks], Al[ks], Al2[ks], bh, bl, bl2, aM[ct], aC[ct]);
            }
        }

        // ---- tanh -> per-wave pl (wave-local LDS round trip) ----
#pragma unroll
        for (int ct = 0; ct < 2; ct++)
#pragma unroll
            for (int i = 0; i < 4; i++) {
                float s1 = aM[ct][i] + aC[ct][i];
                myp[(q * 4 + i) * 34 + ct * 16 + r] = (float)tanh((double)s1);
            }

        // ---- stage 2: S += P_chunk @ C_chunk^T ----
        {
            const float* ps = myp + r * 34 + q * 8;
            float pv[8];
#pragma unroll
            for (int j = 0; j < 8; j++) pv[j] = ps[j];
            bf16x8 ph, plo, pl2;
            split3x8(pv, ph, plo, pl2);
#pragma unroll
            for (int ntS = 0; ntS < 2; ntS++) {
                const size_t base = (size_t)(ntS * 16 + r) * IC + c0 + q * 8;
                bf16x8 ch  = *(const bf16x8*)(Ch  + base);
                bf16x8 cl  = *(const bf16x8*)(Cl  + base);
                bf16x8 cl2 = *(const bf16x8*)(Cl2 + base);
                mfma6(ph, plo, pl2, ch, cl, cl2, saccM[ntS], saccC[ntS]);
            }
        }
    }

#pragma unroll
    for (int ntS = 0; ntS < 2; ntS++)
#pragma unroll
        for (int i = 0; i < 4; i++)
            S[(size_t)(m0 + q * 4 + i) * KK + ntS * 16 + r] = saccM[ntS][i] + saccC[ntS][i];
}

// ---------------------------------------------------------------------------
// K3: softmax over l per (b,k), fp64 math; masked rows -> 1/100. In-place.
// ---------------------------------------------------------------------------
__global__ __launch_bounds__(256) void k3_softmax(float* __restrict__ Sa,
                                                  const int* __restrict__ ni) {
    const int b = blockIdx.x;
    float* Sb = Sa + (size_t)b * LH * KK;
    __shared__ float ls[LH * KK];
    __shared__ double red[8][KK + 1];

    for (int i = threadIdx.x; i < LH * KK; i += 256) ls[i] = Sb[i];
    __syncthreads();

    const int k = threadIdx.x & 31;
    const int grp = threadIdx.x >> 5;
    const int nib = ni[b];

    double vals[13];
    int cnt = 0;
    double vmax = -1e300;
    for (int l = grp; l < LH; l += 8) {
        double v = (double)ls[l * KK + k];
        vals[cnt++] = v;
        vmax = fmax(vmax, v);
    }
    red[grp][k] = vmax;
    __syncthreads();
    if (grp == 0) {
        double m = red[0][k];
        for (int j = 1; j < 8; j++) m = fmax(m, red[j][k]);
        red[0][k] = m;
    }
    __syncthreads();
    const double mx = red[0][k];
    __syncthreads();

    double s = 0.0;
    for (int i = 0; i < cnt; i++) {
        double e = exp(vals[i] - mx);
        vals[i] = e;
        s += e;
    }
    red[grp][k] = s;
    __syncthreads();
    if (grp == 0) {
        double t = 0.0;
        for (int j = 0; j < 8; j++) t += red[j][k];
        red[0][k] = t;
    }
    __syncthreads();
    const double inv = 1.0 / red[0][k];

    float* ab = Sb + k * LH;
    const bool masked = (k >= nib);
    cnt = 0;
    for (int l = grp; l < LH; l += 8) {
        ab[l] = masked ? 0.01f : (float)(vals[cnt] * inv);
        cnt++;
    }
}

// ---------------------------------------------------------------------------
// K4: I[k][d] = sum_l attn[k][l] * H[l][d] (per b), fp32-faithful.
// Restructured: ks-outer, H l-chunk transposed into LDS (zero-filled tail),
// 8 jobs' accumulators in VGPRs. Values identical to R5 kernel.
// ---------------------------------------------------------------------------
__global__ __launch_bounds__(256) void k4_interests(const float* __restrict__ attn,
                                                    const float* __restrict__ H,
                                                    float* __restrict__ I) {
    const int b = blockIdx.x;
    __shared__ float ht[256 * 34];   // 34,816 B: H^T chunk [d][l-l0], pad 34

    const int tid = threadIdx.x;
    const int wave = tid >> 6;
    const int lane = tid & 63;
    const int r = lane & 15, q = lane >> 4;

    const float* Ab = attn + (size_t)b * KK * LH;
    const float* Hb = H + (size_t)b * LH * DD;

    const f32x4 zero = {0.f, 0.f, 0.f, 0.f};
    f32x4 accM[8], accC[8];
#pragma unroll
    for (int jj = 0; jj < 8; jj++) { accM[jj] = zero; accC[jj] = zero; }

    for (int ks = 0; ks < 4; ks++) {
        const int l0c = ks * 32;
        __syncthreads();
        // stage transposed H chunk: l in [l0c, l0c+32) -> ht[d][l-l0c]
        for (int u = tid; u < 32 * 64; u += 256) {
            const int l = u >> 6, dg = u & 63;
            float4 v = {0.f, 0.f, 0.f, 0.f};
            if (l0c + l < LH) v = *(const float4*)(Hb + (size_t)(l0c + l) * DD + dg * 4);
            ht[(dg * 4 + 0) * 34 + l] = v.x;
            ht[(dg * 4 + 1) * 34 + l] = v.y;
            ht[(dg * 4 + 2) * 34 + l] = v.z;
            ht[(dg * 4 + 3) * 34 + l] = v.w;
        }
        __syncthreads();

#pragma unroll
        for (int jj = 0; jj < 8; jj++) {
            const int job = wave + jj * 4;
            const int mt = job & 1, nt = job >> 1;
            const int m0 = mt * 16, n0 = nt * 16;
            float av[8], bv[8];
#pragma unroll
            for (int j = 0; j < 8; j++) {
                const int l = l0c + q * 8 + j;
                av[j] = (l < LH) ? Ab[(size_t)(m0 + r) * LH + l] : 0.f;
            }
            const float* hp = ht + (n0 + r) * 34 + q * 8;
#pragma unroll
            for (int j = 0; j < 8; j++) bv[j] = hp[j];
            bf16x8 ah, al, al2, bh, bl, bl2;
            split3x8(av, ah, al, al2);
            split3x8(bv, bh, bl, bl2);
            mfma6(ah, al, al2, bh, bl, bl2, accM[jj], accC[jj]);
        }
    }

#pragma unroll
    for (int jj = 0; jj < 8; jj++) {
        const int job = wave + jj * 4;
        const int mt = job & 1, nt = job >> 1;
        const int m0 = mt * 16, n0 = nt * 16;
#pragma unroll
        for (int i = 0; i < 4; i++)
            I[((size_t)b * KK + m0 + q * 4 + i) * DD + n0 + r] = accM[jj][i] + accC[jj][i];
    }
}

// ---------------------------------------------------------------------------
// K5: w[n][k] = sum_d cand[n][d]*I[k][d] (fp32-faithful) + variable top-k mask.
// ---------------------------------------------------------------------------
__global__ __launch_bounds__(256) void k5_w_topk(const float* __restrict__ cand,
                                                 const float* __restrict__ I,
                                                 const int* __restrict__ cc,
                                                 float* __restrict__ wm) {
    const int b = blockIdx.x;
    const int wave = threadIdx.x >> 6;
    const int lane = threadIdx.x & 63;
    const int r = lane & 15, q = lane >> 4;

    __shared__ float shw[NC][KK + 1];

    const float* Cb = cand + (size_t)b * NC * DD;
    const float* Ib = I + (size_t)b * KK * DD;

    for (int job = wave; job < 8; job += 4) {
        const int mt = job >> 1, nt = job & 1;
        const int m0 = mt * 16, n0 = nt * 16;
        const f32x4 zero = {0.f, 0.f, 0.f, 0.f};
        f32x4 accM = zero, accC = zero;
#pragma unroll
        for (int ks = 0; ks < 8; ks++) {
            const float* ap = Cb + (size_t)(m0 + r) * DD + ks * 32 + q * 8;
            const float* bp = Ib + (size_t)(n0 + r) * DD + ks * 32 + q * 8;
            float4 u1 = *(const float4*)ap;      float4 u2 = *(const float4*)(ap + 4);
            float4 v1 = *(const float4*)bp;      float4 v2 = *(const float4*)(bp + 4);
            float av[8] = {u1.x,u1.y,u1.z,u1.w,u2.x,u2.y,u2.z,u2.w};
            float bv[8] = {v1.x,v1.y,v1.z,v1.w,v2.x,v2.y,v2.z,v2.w};
            bf16x8 ah, al, al2, bh, bl, bl2;
            split3x8(av, ah, al, al2);
            split3x8(bv, bh, bl, bl2);
            mfma6(ah, al, al2, bh, bl, bl2, accM, accC);
        }
#pragma unroll
        for (int i = 0; i < 4; i++) shw[m0 + q * 4 + i][n0 + r] = accM[i] + accC[i];
    }
    __syncthreads();

    if (threadIdx.x < NC) {
        const int n = threadIdx.x;
        int c8 = 8 * cc[b];
        int dynK = 32 - __clz(c8 - 1);
        dynK = min(max(dynK, 1), KK);
        float v[KK];
        for (int k = 0; k < KK; k++) v[k] = shw[n][k];
        float* dst = wm + ((size_t)b * NC + n) * KK;
        for (int k = 0; k < KK; k++) {
            int rank = 0;
            for (int j = 0; j < KK; j++)
                rank += (v[j] > v[k]) || (v[j] == v[k] && j < k);
            dst[k] = (rank < dynK) ? v[k] : 0.f;
        }
    }
}

// ---------------------------------------------------------------------------
// K6: user[n][d] = sum_k wm[n][k] * I[k][d]  (fp32 out)
// ---------------------------------------------------------------------------
__global__ __launch_bounds__(256) void k6_user(const float* __restrict__ I,
                                               const float* __restrict__ wm,
                                               float* __restrict__ out) {
    const int b = blockIdx.x;
    const int d = threadIdx.x;

    float icol[KK];
    const float* src = I + (size_t)b * KK * DD + d;
#pragma unroll
    for (int k = 0; k < KK; k++) icol[k] = src[(size_t)k * DD];

    const float* wb = wm + (size_t)b * NC * KK;
    for (int n = 0; n < NC; n++) {
        const float* wr = wb + n * KK;
        float acc = 0.f;
#pragma unroll
        for (int k = 0; k < KK; k++) acc += wr[k] * icol[k];
        out[((size_t)b * NC + n) * DD + d] = acc;
    }
}

// ---------------------------------------------------------------------------
extern "C" void kernel_launch(void* const* d_in, const int* in_sizes, int n_in,
                              void* d_out, int out_size, void* d_ws, size_t ws_size,
                              hipStream_t stream) {
    const float* hist = (const float*)d_in[0];
    const float* cand = (const float*)d_in[2];
    const int* ni = (const int*)d_in[3];
    const int* cc = (const int*)d_in[4];
    const float* W = (const float*)d_in[5];
    const float* C = (const float*)d_in[6];
    float* out = (float*)d_out;

    char* w8 = (char*)d_ws;
    float*  S   = (float*)(w8 + 0);
    float*  wm  = (float*)(w8 + 0);
    bf16_t* Wh  = (bf16_t*)(w8 + OFF_WPL);
    bf16_t* Wl  = (bf16_t*)(w8 + OFF_WPL + 131072);
    bf16_t* Wl2 = (bf16_t*)(w8 + OFF_WPL + 262144);
    bf16_t* Ch  = (bf16_t*)(w8 + OFF_CPL);
    bf16_t* Cl  = (bf16_t*)(w8 + OFF_CPL + 16384);
    bf16_t* Cl2 = (bf16_t*)(w8 + OFF_CPL + 32768);
    float*  I   = (float*)(w8 + OFF_I);

    kp_split<<<288, 256, 0, stream>>>(W, C, Wh, Wl, Wl2, Ch, Cl, Cl2);
    k12_proj_scores<<<800, 256, 0, stream>>>(hist, Wh, Wl, Wl2, Ch, Cl, Cl2, S);
    k3_softmax<<<BS, 256, 0, stream>>>(S, ni);
    k4_interests<<<BS, 256, 0, stream>>>(S, hist, I);
    k5_w_topk<<<BS, 256, 0, stream>>>(cand, I, cc, wm);
    k6_user<<<BS, 256, 0, stream>>>(I, wm, out);
}